// Round 3
// baseline (1823.828 us; speedup 1.0000x reference)
//
#include <hip/hip_runtime.h>

// EGNN fused layer, fp32, VALU-bound design.
// Edge kernel: 128 edges/block, 256 threads, 8x8 register tile per thread.
//   layer1: [128e x 305k] @ Wm1[305,128]  (K padded to 320, 5 chunks of 64)
//   layer2: silu(z1) @ Wm2[128,128]       (2 chunk passes, msgT staged in LDS)
//   agg atomicAdd, then coord gate: msg @ Wc1, silu, dot Wc2, clip, 3 atomics.
// Node kernel: 64 nodes/block, concat[h,agg] @ Wn1 (K=256), silu @ Wn2,
//   residual + LayerNorm, x_new = x + coord_delta.

#define H    128
#define ED   48
#define KIN  305   // 2H + ED + 1

__device__ __forceinline__ float silu_f(float v) {
  return v / (1.0f + __expf(-v));
}

// Stage 64 rows x 128 cols of W into sW; rows beyond `rows` are zeroed.
__device__ __forceinline__ void stage_w128(float (*sW)[128], const float* __restrict__ W,
                                           int k0, int rows, int t) {
  #pragma unroll
  for (int i = 0; i < 8; ++i) {
    int f4  = i * 256 + t;        // 0..2047 float4s
    int row = f4 >> 5;            // 32 float4s per row
    int col = (f4 & 31) << 2;
    int gk  = k0 + row;
    float4 v = make_float4(0.f, 0.f, 0.f, 0.f);
    if (gk < rows) v = *(const float4*)&W[(size_t)gk * H + col];
    *(float4*)&sW[row][col] = v;
  }
}

__device__ __forceinline__ void gemm64_8x8(const float (*sIn)[128], const float (*sW)[128],
                                           int ty, int tx, float (&acc)[8][8]) {
  #pragma unroll 4
  for (int kk = 0; kk < 64; ++kk) {
    float4 a0 = *(const float4*)&sIn[kk][ty * 8];
    float4 a1 = *(const float4*)&sIn[kk][ty * 8 + 4];
    float4 w0 = *(const float4*)&sW[kk][tx * 8];
    float4 w1 = *(const float4*)&sW[kk][tx * 8 + 4];
    float a[8] = {a0.x, a0.y, a0.z, a0.w, a1.x, a1.y, a1.z, a1.w};
    float w[8] = {w0.x, w0.y, w0.z, w0.w, w1.x, w1.y, w1.z, w1.w};
    #pragma unroll
    for (int i = 0; i < 8; ++i)
      #pragma unroll
      for (int j = 0; j < 8; ++j)
        acc[i][j] = fmaf(a[i], w[j], acc[i][j]);
  }
}

// Write this thread's 8x8 values (edges=rows of tile, channels) transposed into
// sIn[row=c - pass*64][e] for the next GEMM (K = channel dim).
__device__ __forceinline__ void scatter_T(float (*sIn)[128], const float (&v)[8][8],
                                          int tx, int ty, int pass) {
  if ((tx >> 3) == pass) {
    #pragma unroll
    for (int j = 0; j < 8; ++j) {
      int row = (tx & 7) * 8 + j;
      *(float4*)&sIn[row][ty * 8]     = make_float4(v[0][j], v[1][j], v[2][j], v[3][j]);
      *(float4*)&sIn[row][ty * 8 + 4] = make_float4(v[4][j], v[5][j], v[6][j], v[7][j]);
    }
  }
}

__global__ __launch_bounds__(256, 2)
void egnn_edge_kernel(const float* __restrict__ x, const float* __restrict__ h,
                      const int* __restrict__ ei, const float* __restrict__ ea,
                      const float* __restrict__ Wm1, const float* __restrict__ bm1,
                      const float* __restrict__ Wm2, const float* __restrict__ bm2,
                      const float* __restrict__ Wc1, const float* __restrict__ bc1,
                      const float* __restrict__ Wc2, const float* __restrict__ bc2,
                      float* __restrict__ agg, float* __restrict__ cdelta,
                      int E)
{
  __shared__ float sIn[64][128];
  __shared__ float sW[64][128];
  __shared__ int   sSrc[128];
  __shared__ int   sDst[128];
  __shared__ float sR[3][128];
  __shared__ float sD2[128];

  const int t  = threadIdx.x;
  const int tx = t & 15;   // channel group: c = tx*8 .. tx*8+7
  const int ty = t >> 4;   // edge group:    e = ty*8 .. ty*8+7
  const int eb = blockIdx.x * 128;

  // ---- per-edge preload: src, dst, r_ij, d2
  if (t < 128) {
    int e  = eb + t;
    int ec = (e < E) ? e : (E - 1);
    int s  = ei[ec];
    int d  = ei[E + ec];
    sSrc[t] = s; sDst[t] = d;
    float rx = x[s * 3 + 0] - x[d * 3 + 0];
    float ry = x[s * 3 + 1] - x[d * 3 + 1];
    float rz = x[s * 3 + 2] - x[d * 3 + 2];
    sR[0][t] = rx; sR[1][t] = ry; sR[2][t] = rz;
    sD2[t] = rx * rx + ry * ry + rz * rz;
  }
  __syncthreads();

  // ---------------- layer 1: z1 = msg_input @ Wm1 + bm1 ----------------
  float acc1[8][8];
  #pragma unroll
  for (int i = 0; i < 8; ++i)
    #pragma unroll
    for (int j = 0; j < 8; ++j)
      acc1[i][j] = bm1[tx * 8 + j];

  const int ge = t >> 1;   // edge this thread gathers (2 threads/edge)
  const int gh = t & 1;    // which 32-k half

  for (int ch = 0; ch < 5; ++ch) {
    const int k0 = ch * 64;
    __syncthreads();
    // gather input chunk, transposed: sIn[kk][e]
    if (ch < 4) {
      const int row = (ch < 2) ? sSrc[ge] : sDst[ge];
      const float* __restrict__ hr = &h[(size_t)row * H + ((k0 & 127) + gh * 32)];
      #pragma unroll
      for (int v = 0; v < 8; ++v) {
        float4 val = *(const float4*)&hr[v * 4];
        int kk = gh * 32 + v * 4;
        sIn[kk + 0][ge] = val.x; sIn[kk + 1][ge] = val.y;
        sIn[kk + 2][ge] = val.z; sIn[kk + 3][ge] = val.w;
      }
    } else {
      const int ec = (eb + ge < E) ? (eb + ge) : (E - 1);
      const float* __restrict__ er = &ea[(size_t)ec * ED];
      if (gh == 0) {
        #pragma unroll
        for (int v = 0; v < 8; ++v) {
          float4 val = *(const float4*)&er[v * 4];
          int kk = v * 4;
          sIn[kk + 0][ge] = val.x; sIn[kk + 1][ge] = val.y;
          sIn[kk + 2][ge] = val.z; sIn[kk + 3][ge] = val.w;
        }
      } else {
        #pragma unroll
        for (int v = 0; v < 4; ++v) {
          float4 val = *(const float4*)&er[32 + v * 4];
          int kk = 32 + v * 4;
          sIn[kk + 0][ge] = val.x; sIn[kk + 1][ge] = val.y;
          sIn[kk + 2][ge] = val.z; sIn[kk + 3][ge] = val.w;
        }
        sIn[48][ge] = sD2[ge];
        #pragma unroll
        for (int kk = 49; kk < 64; ++kk) sIn[kk][ge] = 0.f;
      }
    }
    stage_w128(sW, Wm1, k0, KIN, t);
    __syncthreads();
    gemm64_8x8(sIn, sW, ty, tx, acc1);
  }

  // ---------------- layer 2: msg = silu(z1) @ Wm2 + bm2 ----------------
  float sz[8][8];
  #pragma unroll
  for (int i = 0; i < 8; ++i)
    #pragma unroll
    for (int j = 0; j < 8; ++j)
      sz[i][j] = silu_f(acc1[i][j]);

  float acc2[8][8];
  #pragma unroll
  for (int i = 0; i < 8; ++i)
    #pragma unroll
    for (int j = 0; j < 8; ++j)
      acc2[i][j] = bm2[tx * 8 + j];

  for (int pass = 0; pass < 2; ++pass) {
    __syncthreads();
    scatter_T(sIn, sz, tx, ty, pass);
    stage_w128(sW, Wm2, pass * 64, H, t);
    __syncthreads();
    gemm64_8x8(sIn, sW, ty, tx, acc2);
  }

  // ---- agg[dst] += msg (fp32 atomics)
  #pragma unroll
  for (int i = 0; i < 8; ++i) {
    int e = ty * 8 + i;
    if (eb + e < E) {
      float* p = &agg[(size_t)sDst[e] * H + tx * 8];
      #pragma unroll
      for (int j = 0; j < 8; ++j) atomicAdd(&p[j], acc2[i][j]);
    }
  }

  // ---------------- coord gate: z3 = msg @ Wc1 + bc1 ----------------
  float acc3[8][8];
  #pragma unroll
  for (int i = 0; i < 8; ++i)
    #pragma unroll
    for (int j = 0; j < 8; ++j)
      acc3[i][j] = bc1[tx * 8 + j];

  for (int pass = 0; pass < 2; ++pass) {
    __syncthreads();
    scatter_T(sIn, acc2, tx, ty, pass);   // msg (no silu) is the input
    stage_w128(sW, Wc1, pass * 64, H, t);
    __syncthreads();
    gemm64_8x8(sIn, sW, ty, tx, acc3);
  }

  // w = clip(silu(z3) . Wc2 + bc2, -1, 1); coord_delta[dst] += w * r_ij
  float wc2r[8];
  #pragma unroll
  for (int j = 0; j < 8; ++j) wc2r[j] = Wc2[tx * 8 + j];
  const float bc2v = bc2[0];

  #pragma unroll
  for (int i = 0; i < 8; ++i) {
    float wp = 0.f;
    #pragma unroll
    for (int j = 0; j < 8; ++j) wp = fmaf(silu_f(acc3[i][j]), wc2r[j], wp);
    #pragma unroll
    for (int m = 1; m < 16; m <<= 1) wp += __shfl_xor(wp, m);
    if (tx == 0) {
      int e = ty * 8 + i;
      if (eb + e < E) {
        float wv = wp + bc2v;
        wv = fminf(fmaxf(wv, -1.0f), 1.0f);
        int d = sDst[e];
        atomicAdd(&cdelta[(size_t)d * 3 + 0], wv * sR[0][e]);
        atomicAdd(&cdelta[(size_t)d * 3 + 1], wv * sR[1][e]);
        atomicAdd(&cdelta[(size_t)d * 3 + 2], wv * sR[2][e]);
      }
    }
  }
}

__global__ __launch_bounds__(256, 2)
void egnn_node_kernel(const float* __restrict__ x, const float* __restrict__ h,
                      const float* __restrict__ agg,
                      const float* __restrict__ Wn1, const float* __restrict__ bn1,
                      const float* __restrict__ Wn2, const float* __restrict__ bn2,
                      const float* __restrict__ gamma, const float* __restrict__ beta,
                      const float* __restrict__ cdelta,
                      float* __restrict__ out_x, float* __restrict__ out_h, int N)
{
  __shared__ float sIn[64][64];
  __shared__ float sW[64][128];

  const int t  = threadIdx.x;
  const int tx = t & 15;   // channel group: c = tx*8..
  const int ty = t >> 4;   // node group: n = ty*4..
  const int nb = blockIdx.x * 64;

  float acc1[4][8];
  #pragma unroll
  for (int i = 0; i < 4; ++i)
    #pragma unroll
    for (int j = 0; j < 8; ++j)
      acc1[i][j] = bn1[tx * 8 + j];

  const int nl = t >> 2;   // node this thread gathers (4 threads/node)
  const int q  = t & 3;
  const int ng = nb + nl;

  for (int ch = 0; ch < 4; ++ch) {
    const int k0 = ch * 64;
    __syncthreads();
    const float* __restrict__ src = (ch < 2) ? h : agg;
    const int koff = (k0 & 127) + q * 16;
    if (ng < N) {
      const float* __restrict__ row = &src[(size_t)ng * H + koff];
      #pragma unroll
      for (int v = 0; v < 4; ++v) {
        float4 val = *(const float4*)&row[v * 4];
        int kk = q * 16 + v * 4;
        sIn[kk + 0][nl] = val.x; sIn[kk + 1][nl] = val.y;
        sIn[kk + 2][nl] = val.z; sIn[kk + 3][nl] = val.w;
      }
    } else {
      #pragma unroll
      for (int v = 0; v < 16; ++v) sIn[q * 16 + v][nl] = 0.f;
    }
    stage_w128(sW, Wn1, k0, 2 * H, t);
    __syncthreads();
    #pragma unroll 4
    for (int kk = 0; kk < 64; ++kk) {
      float4 a0 = *(const float4*)&sIn[kk][ty * 4];
      float4 w0 = *(const float4*)&sW[kk][tx * 8];
      float4 w1 = *(const float4*)&sW[kk][tx * 8 + 4];
      float a[4] = {a0.x, a0.y, a0.z, a0.w};
      float w[8] = {w0.x, w0.y, w0.z, w0.w, w1.x, w1.y, w1.z, w1.w};
      #pragma unroll
      for (int i = 0; i < 4; ++i)
        #pragma unroll
        for (int j = 0; j < 8; ++j)
          acc1[i][j] = fmaf(a[i], w[j], acc1[i][j]);
    }
  }

  float sz[4][8];
  #pragma unroll
  for (int i = 0; i < 4; ++i)
    #pragma unroll
    for (int j = 0; j < 8; ++j)
      sz[i][j] = silu_f(acc1[i][j]);

  float acc2[4][8];
  #pragma unroll
  for (int i = 0; i < 4; ++i)
    #pragma unroll
    for (int j = 0; j < 8; ++j)
      acc2[i][j] = bn2[tx * 8 + j];

  for (int pass = 0; pass < 2; ++pass) {
    __syncthreads();
    if ((tx >> 3) == pass) {
      #pragma unroll
      for (int j = 0; j < 8; ++j) {
        int row = (tx & 7) * 8 + j;
        *(float4*)&sIn[row][ty * 4] = make_float4(sz[0][j], sz[1][j], sz[2][j], sz[3][j]);
      }
    }
    stage_w128(sW, Wn2, pass * 64, H, t);
    __syncthreads();
    #pragma unroll 4
    for (int kk = 0; kk < 64; ++kk) {
      float4 a0 = *(const float4*)&sIn[kk][ty * 4];
      float4 w0 = *(const float4*)&sW[kk][tx * 8];
      float4 w1 = *(const float4*)&sW[kk][tx * 8 + 4];
      float a[4] = {a0.x, a0.y, a0.z, a0.w};
      float w[8] = {w0.x, w0.y, w0.z, w0.w, w1.x, w1.y, w1.z, w1.w};
      #pragma unroll
      for (int i = 0; i < 4; ++i)
        #pragma unroll
        for (int j = 0; j < 8; ++j)
          acc2[i][j] = fmaf(a[i], w[j], acc2[i][j]);
    }
  }

  // residual + LayerNorm + store h_new
  #pragma unroll
  for (int i = 0; i < 4; ++i) {
    int n = nb + ty * 4 + i;
    float4 h0, h1;
    float v[8];
    if (n < N) {
      h0 = *(const float4*)&h[(size_t)n * H + tx * 8];
      h1 = *(const float4*)&h[(size_t)n * H + tx * 8 + 4];
    } else {
      h0 = make_float4(0, 0, 0, 0); h1 = h0;
    }
    v[0] = acc2[i][0] + h0.x; v[1] = acc2[i][1] + h0.y;
    v[2] = acc2[i][2] + h0.z; v[3] = acc2[i][3] + h0.w;
    v[4] = acc2[i][4] + h1.x; v[5] = acc2[i][5] + h1.y;
    v[6] = acc2[i][6] + h1.z; v[7] = acc2[i][7] + h1.w;
    float s = 0.f, sq = 0.f;
    #pragma unroll
    for (int j = 0; j < 8; ++j) { s += v[j]; sq += v[j] * v[j]; }
    #pragma unroll
    for (int m = 1; m < 16; m <<= 1) { s += __shfl_xor(s, m); sq += __shfl_xor(sq, m); }
    float mu  = s * (1.0f / 128.0f);
    float var = sq * (1.0f / 128.0f) - mu * mu;
    float rs  = rsqrtf(var + 1e-5f);
    if (n < N) {
      float4 g0 = *(const float4*)&gamma[tx * 8];
      float4 g1 = *(const float4*)&gamma[tx * 8 + 4];
      float4 b0 = *(const float4*)&beta[tx * 8];
      float4 b1 = *(const float4*)&beta[tx * 8 + 4];
      float4 o0, o1;
      o0.x = (v[0] - mu) * rs * g0.x + b0.x;
      o0.y = (v[1] - mu) * rs * g0.y + b0.y;
      o0.z = (v[2] - mu) * rs * g0.z + b0.z;
      o0.w = (v[3] - mu) * rs * g0.w + b0.w;
      o1.x = (v[4] - mu) * rs * g1.x + b1.x;
      o1.y = (v[5] - mu) * rs * g1.y + b1.y;
      o1.z = (v[6] - mu) * rs * g1.z + b1.z;
      o1.w = (v[7] - mu) * rs * g1.w + b1.w;
      *(float4*)&out_h[(size_t)n * H + tx * 8]     = o0;
      *(float4*)&out_h[(size_t)n * H + tx * 8 + 4] = o1;
    }
  }

  // x_new = x + coord_delta
  if (t < 192) {
    int nl2 = t / 3, c = t - nl2 * 3;
    int n = nb + nl2;
    if (n < N)
      out_x[(size_t)n * 3 + c] = x[(size_t)n * 3 + c] + cdelta[(size_t)n * 3 + c];
  }
}

extern "C" void kernel_launch(void* const* d_in, const int* in_sizes, int n_in,
                              void* d_out, int out_size, void* d_ws, size_t ws_size,
                              hipStream_t stream) {
  const float* x     = (const float*)d_in[0];
  const float* h     = (const float*)d_in[1];
  const int*   ei    = (const int*)d_in[2];
  const float* ea    = (const float*)d_in[3];
  const float* Wm1   = (const float*)d_in[4];
  const float* bm1   = (const float*)d_in[5];
  const float* Wm2   = (const float*)d_in[6];
  const float* bm2   = (const float*)d_in[7];
  const float* Wn1   = (const float*)d_in[8];
  const float* bn1   = (const float*)d_in[9];
  const float* Wn2   = (const float*)d_in[10];
  const float* bn2   = (const float*)d_in[11];
  const float* Wc1   = (const float*)d_in[12];
  const float* bc1   = (const float*)d_in[13];
  const float* Wc2   = (const float*)d_in[14];
  const float* bc2   = (const float*)d_in[15];
  const float* gamma = (const float*)d_in[16];
  const float* beta  = (const float*)d_in[17];

  const int N = in_sizes[0] / 3;
  const int E = in_sizes[2] / 2;

  float* agg    = (float*)d_ws;
  float* cdelta = agg + (size_t)N * H;
  float* out_x  = (float*)d_out;
  float* out_h  = out_x + (size_t)N * 3;

  hipMemsetAsync(d_ws, 0, (size_t)(N * H + N * 3) * sizeof(float), stream);

  const int eblocks = (E + 127) / 128;
  egnn_edge_kernel<<<eblocks, 256, 0, stream>>>(
      x, h, ei, ea, Wm1, bm1, Wm2, bm2, Wc1, bc1, Wc2, bc2, agg, cdelta, E);

  const int nblocks = (N + 63) / 64;
  egnn_node_kernel<<<nblocks, 256, 0, stream>>>(
      x, h, agg, Wn1, bn1, Wn2, bn2, gamma, beta, cdelta, out_x, out_h, N);
}

// Round 4
// 561.143 us; speedup vs baseline: 3.2502x; 3.2502x over previous
//
#include <hip/hip_runtime.h>

// EGNN fused layer. Edge kernel rewritten with MFMA bf16 (fp32 accumulate).
//   Round-3 evidence: fp32 VALU version was LDS-read-throughput-bound
//   (VALUBusy 28.7%, 8.3e7 bank conflicts, model matched 1725us). MFMA raises
//   FLOP/LDS-byte ~8x. Weights+activations cast to bf16 (harness compares at
//   bf16 granularity: fp32 kernel's absmax was exactly 1 bf16 ulp @ 2.0).
// Edge kernel: 128 edges/block, 4 waves, each wave 32edges x 128cols.
//   L1: [128 x 320pad] @ Wm1 -> 5 K-chunks of 64. L2: silu @ Wm2. agg atomics.
//   L3 gate: msg @ Wc1, silu, dot Wc2, clip, cdelta atomics.
// LDS tiles XOR-swizzled (chunk ^= row&7) -> even bank-quad spread on b128.
// Node kernel: unchanged fp32 VALU (only ~2% of FLOPs).

#define H    128
#define ED   48
#define KIN  305   // 2H + ED + 1

typedef __attribute__((ext_vector_type(8))) short bf16x8;
typedef __attribute__((ext_vector_type(4))) float f32x4;

__device__ __forceinline__ float silu_f(float v) {
  return v / (1.0f + __expf(-v));
}

__device__ __forceinline__ unsigned short f2bf(float f) {
  unsigned u = __float_as_uint(f);
  return (unsigned short)((u + 0x7FFFu + ((u >> 16) & 1u)) >> 16);
}

// Stage W[k0..k0+64) rows (f32, row-major [rows][128]) into sB as bf16,
// TRANSPOSED: sB layout [col][k_local] with 16B-chunk XOR swizzle (^ col&7).
__device__ __forceinline__ void stage_bt(unsigned short* sB, const float* __restrict__ W,
                                         int k0, int rows, int t) {
  #pragma unroll
  for (int q = 0; q < 8; ++q) {
    int idx = q * 256 + t;
    int cq  = idx & 31;        // col quad 0..31
    int kl  = idx >> 5;        // k_local 0..63
    int gk  = k0 + kl;
    float4 f = make_float4(0.f, 0.f, 0.f, 0.f);
    if (gk < rows) f = *(const float4*)&W[(size_t)gk * H + cq * 4];
    #pragma unroll
    for (int d = 0; d < 4; ++d) {
      int col = cq * 4 + d;
      float fv = (d == 0) ? f.x : (d == 1) ? f.y : (d == 2) ? f.z : f.w;
      sB[col * 64 + (((kl >> 3) ^ (col & 7)) << 3) + (kl & 7)] = f2bf(fv);
    }
  }
}

// Build one 16B chunk (8 bf16) from two float4s and store swizzled.
__device__ __forceinline__ void store_chunk(unsigned short* sA, int e, int ck,
                                            float4 f0, float4 f1) {
  bf16x8 pk;
  pk[0] = (short)f2bf(f0.x); pk[1] = (short)f2bf(f0.y);
  pk[2] = (short)f2bf(f0.z); pk[3] = (short)f2bf(f0.w);
  pk[4] = (short)f2bf(f1.x); pk[5] = (short)f2bf(f1.y);
  pk[6] = (short)f2bf(f1.z); pk[7] = (short)f2bf(f1.w);
  *(bf16x8*)&sA[e * 64 + ((ck ^ (e & 7)) << 3)] = pk;
}

__global__ __launch_bounds__(256, 2)
void egnn_edge_mfma(const float* __restrict__ x, const float* __restrict__ h,
                    const int* __restrict__ ei, const float* __restrict__ ea,
                    const float* __restrict__ Wm1, const float* __restrict__ bm1,
                    const float* __restrict__ Wm2, const float* __restrict__ bm2,
                    const float* __restrict__ Wc1, const float* __restrict__ bc1,
                    const float* __restrict__ Wc2, const float* __restrict__ bc2,
                    float* __restrict__ agg, float* __restrict__ cdelta, int E)
{
  __shared__ unsigned short sA[128 * 64];  // A tile [e][k] swizzled, 16KB
  __shared__ unsigned short sB[128 * 64];  // B tile W^T [col][k] swizzled, 16KB
  __shared__ int   sSrc[128], sDst[128];
  __shared__ float sR[3][128];

  const int t    = threadIdx.x;
  const int lane = t & 63;
  const int wv   = t >> 6;       // wave 0..3 -> edges [wv*32, wv*32+32)
  const int lr   = lane & 15;    // fragment 16-index
  const int lg   = lane >> 4;    // k-group 0..3
  const int eb   = blockIdx.x * 128;

  if (t < 128) {
    int e  = eb + t;
    int ec = (e < E) ? e : (E - 1);
    int s  = ei[ec];
    int d  = ei[E + ec];
    sSrc[t] = s; sDst[t] = d;
    float rx = x[s * 3 + 0] - x[d * 3 + 0];
    float ry = x[s * 3 + 1] - x[d * 3 + 1];
    float rz = x[s * 3 + 2] - x[d * 3 + 2];
    sR[0][t] = rx; sR[1][t] = ry; sR[2][t] = rz;
  }

  // ---------------- layer 1: z1 = msg_input @ Wm1 + bm1 ----------------
  f32x4 acc1[8][2];
  #pragma unroll
  for (int ct = 0; ct < 8; ++ct) {
    float b = bm1[ct * 16 + lr];
    #pragma unroll
    for (int rt = 0; rt < 2; ++rt) {
      acc1[ct][rt][0] = b; acc1[ct][rt][1] = b;
      acc1[ct][rt][2] = b; acc1[ct][rt][3] = b;
    }
  }

  const int se = t >> 1;   // edge this thread stages
  const int sh = t & 1;    // which 32-k half

  for (int ch = 0; ch < 5; ++ch) {
    __syncthreads();
    // ---- stage A chunk (global f32 -> bf16 -> LDS, swizzled)
    if (ch < 4) {
      int row = (ch < 2) ? sSrc[se] : sDst[se];
      const float* __restrict__ hp = &h[(size_t)row * H + (ch & 1) * 64 + sh * 32];
      #pragma unroll
      for (int c = 0; c < 4; ++c) {
        float4 f0 = *(const float4*)&hp[c * 8];
        float4 f1 = *(const float4*)&hp[c * 8 + 4];
        store_chunk(sA, se, sh * 4 + c, f0, f1);
      }
    } else {
      int ecl = (eb + se < E) ? (eb + se) : (E - 1);
      if (sh == 0) {
        const float* __restrict__ ep = &ea[(size_t)ecl * ED];
        #pragma unroll
        for (int c = 0; c < 4; ++c) {
          float4 f0 = *(const float4*)&ep[c * 8];
          float4 f1 = *(const float4*)&ep[c * 8 + 4];
          store_chunk(sA, se, c, f0, f1);
        }
      } else {
        const float* __restrict__ ep = &ea[(size_t)ecl * ED + 32];
        float4 f0 = *(const float4*)&ep[0];
        float4 f1 = *(const float4*)&ep[4];
        store_chunk(sA, se, 4, f0, f1);
        f0 = *(const float4*)&ep[8];
        f1 = *(const float4*)&ep[12];
        store_chunk(sA, se, 5, f0, f1);
        float rx = sR[0][se], ry = sR[1][se], rz = sR[2][se];
        float d2 = rx * rx + ry * ry + rz * rz;
        store_chunk(sA, se, 6, make_float4(d2, 0.f, 0.f, 0.f),
                    make_float4(0.f, 0.f, 0.f, 0.f));
        store_chunk(sA, se, 7, make_float4(0.f, 0.f, 0.f, 0.f),
                    make_float4(0.f, 0.f, 0.f, 0.f));
      }
    }
    stage_bt(sB, Wm1, ch * 64, KIN, t);
    __syncthreads();
    // ---- mfma: 2 K-steps of 32
    #pragma unroll
    for (int s = 0; s < 2; ++s) {
      bf16x8 a0, a1;
      {
        int e0 = wv * 32 + lr;
        int e1 = wv * 32 + 16 + lr;
        int ck = s * 4 + lg;
        a0 = *(const bf16x8*)&sA[e0 * 64 + ((ck ^ (e0 & 7)) << 3)];
        a1 = *(const bf16x8*)&sA[e1 * 64 + ((ck ^ (e1 & 7)) << 3)];
      }
      #pragma unroll
      for (int ct = 0; ct < 8; ++ct) {
        int col = ct * 16 + lr;
        int ck  = s * 4 + lg;
        bf16x8 b = *(const bf16x8*)&sB[col * 64 + ((ck ^ (col & 7)) << 3)];
        acc1[ct][0] = __builtin_amdgcn_mfma_f32_16x16x32_bf16(a0, b, acc1[ct][0], 0, 0, 0);
        acc1[ct][1] = __builtin_amdgcn_mfma_f32_16x16x32_bf16(a1, b, acc1[ct][1], 0, 0, 0);
      }
    }
  }

  // ---------------- layer 2: msg = silu(z1) @ Wm2 + bm2 ----------------
  f32x4 acc2[8][2];
  #pragma unroll
  for (int ct = 0; ct < 8; ++ct) {
    float b = bm2[ct * 16 + lr];
    #pragma unroll
    for (int rt = 0; rt < 2; ++rt) {
      acc2[ct][rt][0] = b; acc2[ct][rt][1] = b;
      acc2[ct][rt][2] = b; acc2[ct][rt][3] = b;
    }
  }

  for (int p = 0; p < 2; ++p) {
    __syncthreads();
    // scatter silu(acc1) cols [p*64,p*64+64) into sA as [e][k_local] bf16
    #pragma unroll
    for (int ci = 0; ci < 4; ++ci) {
      int ct = p * 4 + ci;
      int kl = ci * 16 + lr;
      int ck = kl >> 3;
      #pragma unroll
      for (int rt = 0; rt < 2; ++rt) {
        #pragma unroll
        for (int r = 0; r < 4; ++r) {
          int e = wv * 32 + rt * 16 + lg * 4 + r;
          sA[e * 64 + ((ck ^ (e & 7)) << 3) + (kl & 7)] = f2bf(silu_f(acc1[ct][rt][r]));
        }
      }
    }
    stage_bt(sB, Wm2, p * 64, H, t);
    __syncthreads();
    #pragma unroll
    for (int s = 0; s < 2; ++s) {
      bf16x8 a0, a1;
      {
        int e0 = wv * 32 + lr;
        int e1 = wv * 32 + 16 + lr;
        int ck = s * 4 + lg;
        a0 = *(const bf16x8*)&sA[e0 * 64 + ((ck ^ (e0 & 7)) << 3)];
        a1 = *(const bf16x8*)&sA[e1 * 64 + ((ck ^ (e1 & 7)) << 3)];
      }
      #pragma unroll
      for (int ct = 0; ct < 8; ++ct) {
        int col = ct * 16 + lr;
        int ck  = s * 4 + lg;
        bf16x8 b = *(const bf16x8*)&sB[col * 64 + ((ck ^ (col & 7)) << 3)];
        acc2[ct][0] = __builtin_amdgcn_mfma_f32_16x16x32_bf16(a0, b, acc2[ct][0], 0, 0, 0);
        acc2[ct][1] = __builtin_amdgcn_mfma_f32_16x16x32_bf16(a1, b, acc2[ct][1], 0, 0, 0);
      }
    }
  }

  // ---- agg[dst] += msg (fp32 atomics, from C-layout regs)
  #pragma unroll
  for (int ct = 0; ct < 8; ++ct) {
    int col = ct * 16 + lr;
    #pragma unroll
    for (int rt = 0; rt < 2; ++rt) {
      #pragma unroll
      for (int r = 0; r < 4; ++r) {
        int el = wv * 32 + rt * 16 + lg * 4 + r;
        if (eb + el < E)
          atomicAdd(&agg[(size_t)sDst[el] * H + col], acc2[ct][rt][r]);
      }
    }
  }

  // ---------------- layer 3 gate: z3 = msg @ Wc1 + bc1 ----------------
  f32x4 acc3[8][2];
  #pragma unroll
  for (int ct = 0; ct < 8; ++ct) {
    float b = bc1[ct * 16 + lr];
    #pragma unroll
    for (int rt = 0; rt < 2; ++rt) {
      acc3[ct][rt][0] = b; acc3[ct][rt][1] = b;
      acc3[ct][rt][2] = b; acc3[ct][rt][3] = b;
    }
  }

  for (int p = 0; p < 2; ++p) {
    __syncthreads();
    #pragma unroll
    for (int ci = 0; ci < 4; ++ci) {
      int ct = p * 4 + ci;
      int kl = ci * 16 + lr;
      int ck = kl >> 3;
      #pragma unroll
      for (int rt = 0; rt < 2; ++rt) {
        #pragma unroll
        for (int r = 0; r < 4; ++r) {
          int e = wv * 32 + rt * 16 + lg * 4 + r;
          sA[e * 64 + ((ck ^ (e & 7)) << 3) + (kl & 7)] = f2bf(acc2[ct][rt][r]);
        }
      }
    }
    stage_bt(sB, Wc1, p * 64, H, t);
    __syncthreads();
    #pragma unroll
    for (int s = 0; s < 2; ++s) {
      bf16x8 a0, a1;
      {
        int e0 = wv * 32 + lr;
        int e1 = wv * 32 + 16 + lr;
        int ck = s * 4 + lg;
        a0 = *(const bf16x8*)&sA[e0 * 64 + ((ck ^ (e0 & 7)) << 3)];
        a1 = *(const bf16x8*)&sA[e1 * 64 + ((ck ^ (e1 & 7)) << 3)];
      }
      #pragma unroll
      for (int ct = 0; ct < 8; ++ct) {
        int col = ct * 16 + lr;
        int ck  = s * 4 + lg;
        bf16x8 b = *(const bf16x8*)&sB[col * 64 + ((ck ^ (col & 7)) << 3)];
        acc3[ct][0] = __builtin_amdgcn_mfma_f32_16x16x32_bf16(a0, b, acc3[ct][0], 0, 0, 0);
        acc3[ct][1] = __builtin_amdgcn_mfma_f32_16x16x32_bf16(a1, b, acc3[ct][1], 0, 0, 0);
      }
    }
  }

  // w = clip(silu(z3) . Wc2 + bc2, -1, 1); coord_delta[dst] += w * r_ij
  float wsum[2][4];
  #pragma unroll
  for (int rt = 0; rt < 2; ++rt)
    #pragma unroll
    for (int r = 0; r < 4; ++r) wsum[rt][r] = 0.f;

  #pragma unroll
  for (int ct = 0; ct < 8; ++ct) {
    float wc = Wc2[ct * 16 + lr];
    #pragma unroll
    for (int rt = 0; rt < 2; ++rt)
      #pragma unroll
      for (int r = 0; r < 4; ++r)
        wsum[rt][r] = fmaf(silu_f(acc3[ct][rt][r]), wc, wsum[rt][r]);
  }
  const float bc2v = bc2[0];
  #pragma unroll
  for (int rt = 0; rt < 2; ++rt) {
    #pragma unroll
    for (int r = 0; r < 4; ++r) {
      float s = wsum[rt][r];
      s += __shfl_xor(s, 1); s += __shfl_xor(s, 2);
      s += __shfl_xor(s, 4); s += __shfl_xor(s, 8);
      int el = wv * 32 + rt * 16 + lg * 4 + r;
      if (lr == 0 && eb + el < E) {
        float wval = fminf(fmaxf(s + bc2v, -1.0f), 1.0f);
        int d = sDst[el];
        atomicAdd(&cdelta[(size_t)d * 3 + 0], wval * sR[0][el]);
        atomicAdd(&cdelta[(size_t)d * 3 + 1], wval * sR[1][el]);
        atomicAdd(&cdelta[(size_t)d * 3 + 2], wval * sR[2][el]);
      }
    }
  }
}

// ---------------- node kernel: unchanged fp32 VALU ----------------
__device__ __forceinline__ void stage_w128(float (*sW)[128], const float* __restrict__ W,
                                           int k0, int rows, int t) {
  #pragma unroll
  for (int i = 0; i < 8; ++i) {
    int f4  = i * 256 + t;
    int row = f4 >> 5;
    int col = (f4 & 31) << 2;
    int gk  = k0 + row;
    float4 v = make_float4(0.f, 0.f, 0.f, 0.f);
    if (gk < rows) v = *(const float4*)&W[(size_t)gk * H + col];
    *(float4*)&sW[row][col] = v;
  }
}

__global__ __launch_bounds__(256, 2)
void egnn_node_kernel(const float* __restrict__ x, const float* __restrict__ h,
                      const float* __restrict__ agg,
                      const float* __restrict__ Wn1, const float* __restrict__ bn1,
                      const float* __restrict__ Wn2, const float* __restrict__ bn2,
                      const float* __restrict__ gamma, const float* __restrict__ beta,
                      const float* __restrict__ cdelta,
                      float* __restrict__ out_x, float* __restrict__ out_h, int N)
{
  __shared__ float sIn[64][64];
  __shared__ float sW[64][128];

  const int t  = threadIdx.x;
  const int tx = t & 15;
  const int ty = t >> 4;
  const int nb = blockIdx.x * 64;

  float acc1[4][8];
  #pragma unroll
  for (int i = 0; i < 4; ++i)
    #pragma unroll
    for (int j = 0; j < 8; ++j)
      acc1[i][j] = bn1[tx * 8 + j];

  const int nl = t >> 2;
  const int q  = t & 3;
  const int ng = nb + nl;

  for (int ch = 0; ch < 4; ++ch) {
    const int k0 = ch * 64;
    __syncthreads();
    const float* __restrict__ src = (ch < 2) ? h : agg;
    const int koff = (k0 & 127) + q * 16;
    if (ng < N) {
      const float* __restrict__ row = &src[(size_t)ng * H + koff];
      #pragma unroll
      for (int v = 0; v < 4; ++v) {
        float4 val = *(const float4*)&row[v * 4];
        int kk = q * 16 + v * 4;
        sIn[kk + 0][nl] = val.x; sIn[kk + 1][nl] = val.y;
        sIn[kk + 2][nl] = val.z; sIn[kk + 3][nl] = val.w;
      }
    } else {
      #pragma unroll
      for (int v = 0; v < 16; ++v) sIn[q * 16 + v][nl] = 0.f;
    }
    stage_w128(sW, Wn1, k0, 2 * H, t);
    __syncthreads();
    #pragma unroll 4
    for (int kk = 0; kk < 64; ++kk) {
      float4 a0 = *(const float4*)&sIn[kk][ty * 4];
      float4 w0 = *(const float4*)&sW[kk][tx * 8];
      float4 w1 = *(const float4*)&sW[kk][tx * 8 + 4];
      float a[4] = {a0.x, a0.y, a0.z, a0.w};
      float w[8] = {w0.x, w0.y, w0.z, w0.w, w1.x, w1.y, w1.z, w1.w};
      #pragma unroll
      for (int i = 0; i < 4; ++i)
        #pragma unroll
        for (int j = 0; j < 8; ++j)
          acc1[i][j] = fmaf(a[i], w[j], acc1[i][j]);
    }
  }

  float sz[4][8];
  #pragma unroll
  for (int i = 0; i < 4; ++i)
    #pragma unroll
    for (int j = 0; j < 8; ++j)
      sz[i][j] = silu_f(acc1[i][j]);

  float acc2[4][8];
  #pragma unroll
  for (int i = 0; i < 4; ++i)
    #pragma unroll
    for (int j = 0; j < 8; ++j)
      acc2[i][j] = bn2[tx * 8 + j];

  for (int pass = 0; pass < 2; ++pass) {
    __syncthreads();
    if ((tx >> 3) == pass) {
      #pragma unroll
      for (int j = 0; j < 8; ++j) {
        int row = (tx & 7) * 8 + j;
        *(float4*)&sIn[row][ty * 4] = make_float4(sz[0][j], sz[1][j], sz[2][j], sz[3][j]);
      }
    }
    stage_w128(sW, Wn2, pass * 64, H, t);
    __syncthreads();
    #pragma unroll 4
    for (int kk = 0; kk < 64; ++kk) {
      float4 a0 = *(const float4*)&sIn[kk][ty * 4];
      float4 w0 = *(const float4*)&sW[kk][tx * 8];
      float4 w1 = *(const float4*)&sW[kk][tx * 8 + 4];
      float a[4] = {a0.x, a0.y, a0.z, a0.w};
      float w[8] = {w0.x, w0.y, w0.z, w0.w, w1.x, w1.y, w1.z, w1.w};
      #pragma unroll
      for (int i = 0; i < 4; ++i)
        #pragma unroll
        for (int j = 0; j < 8; ++j)
          acc2[i][j] = fmaf(a[i], w[j], acc2[i][j]);
    }
  }

  #pragma unroll
  for (int i = 0; i < 4; ++i) {
    int n = nb + ty * 4 + i;
    float4 h0, h1;
    float v[8];
    if (n < N) {
      h0 = *(const float4*)&h[(size_t)n * H + tx * 8];
      h1 = *(const float4*)&h[(size_t)n * H + tx * 8 + 4];
    } else {
      h0 = make_float4(0, 0, 0, 0); h1 = h0;
    }
    v[0] = acc2[i][0] + h0.x; v[1] = acc2[i][1] + h0.y;
    v[2] = acc2[i][2] + h0.z; v[3] = acc2[i][3] + h0.w;
    v[4] = acc2[i][4] + h1.x; v[5] = acc2[i][5] + h1.y;
    v[6] = acc2[i][6] + h1.z; v[7] = acc2[i][7] + h1.w;
    float s = 0.f, sq = 0.f;
    #pragma unroll
    for (int j = 0; j < 8; ++j) { s += v[j]; sq += v[j] * v[j]; }
    #pragma unroll
    for (int m = 1; m < 16; m <<= 1) { s += __shfl_xor(s, m); sq += __shfl_xor(sq, m); }
    float mu  = s * (1.0f / 128.0f);
    float var = sq * (1.0f / 128.0f) - mu * mu;
    float rs  = rsqrtf(var + 1e-5f);
    if (n < N) {
      float4 g0 = *(const float4*)&gamma[tx * 8];
      float4 g1 = *(const float4*)&gamma[tx * 8 + 4];
      float4 b0 = *(const float4*)&beta[tx * 8];
      float4 b1 = *(const float4*)&beta[tx * 8 + 4];
      float4 o0, o1;
      o0.x = (v[0] - mu) * rs * g0.x + b0.x;
      o0.y = (v[1] - mu) * rs * g0.y + b0.y;
      o0.z = (v[2] - mu) * rs * g0.z + b0.z;
      o0.w = (v[3] - mu) * rs * g0.w + b0.w;
      o1.x = (v[4] - mu) * rs * g1.x + b1.x;
      o1.y = (v[5] - mu) * rs * g1.y + b1.y;
      o1.z = (v[6] - mu) * rs * g1.z + b1.z;
      o1.w = (v[7] - mu) * rs * g1.w + b1.w;
      *(float4*)&out_h[(size_t)n * H + tx * 8]     = o0;
      *(float4*)&out_h[(size_t)n * H + tx * 8 + 4] = o1;
    }
  }

  if (t < 192) {
    int nl2 = t / 3, c = t - nl2 * 3;
    int n = nb + nl2;
    if (n < N)
      out_x[(size_t)n * 3 + c] = x[(size_t)n * 3 + c] + cdelta[(size_t)n * 3 + c];
  }
}

extern "C" void kernel_launch(void* const* d_in, const int* in_sizes, int n_in,
                              void* d_out, int out_size, void* d_ws, size_t ws_size,
                              hipStream_t stream) {
  const float* x     = (const float*)d_in[0];
  const float* h     = (const float*)d_in[1];
  const int*   ei    = (const int*)d_in[2];
  const float* ea    = (const float*)d_in[3];
  const float* Wm1   = (const float*)d_in[4];
  const float* bm1   = (const float*)d_in[5];
  const float* Wm2   = (const float*)d_in[6];
  const float* bm2   = (const float*)d_in[7];
  const float* Wn1   = (const float*)d_in[8];
  const float* bn1   = (const float*)d_in[9];
  const float* Wn2   = (const float*)d_in[10];
  const float* bn2   = (const float*)d_in[11];
  const float* Wc1   = (const float*)d_in[12];
  const float* bc1   = (const float*)d_in[13];
  const float* Wc2   = (const float*)d_in[14];
  const float* bc2   = (const float*)d_in[15];
  const float* gamma = (const float*)d_in[16];
  const float* beta  = (const float*)d_in[17];

  const int N = in_sizes[0] / 3;
  const int E = in_sizes[2] / 2;

  float* agg    = (float*)d_ws;
  float* cdelta = agg + (size_t)N * H;
  float* out_x  = (float*)d_out;
  float* out_h  = out_x + (size_t)N * 3;

  hipMemsetAsync(d_ws, 0, (size_t)(N * H + N * 3) * sizeof(float), stream);

  const int eblocks = (E + 127) / 128;
  egnn_edge_mfma<<<eblocks, 256, 0, stream>>>(
      x, h, ei, ea, Wm1, bm1, Wm2, bm2, Wc1, bc1, Wc2, bc2, agg, cdelta, E);

  const int nblocks = (N + 63) / 64;
  egnn_node_kernel<<<nblocks, 256, 0, stream>>>(
      x, h, agg, Wn1, bn1, Wn2, bn2, gamma, beta, cdelta, out_x, out_h, N);
}

// Round 5
// 457.912 us; speedup vs baseline: 3.9829x; 1.2254x over previous
//
#include <hip/hip_runtime.h>

// EGNN fused layer, MFMA bf16 edge kernel with DMA staging.
// R4 evidence: MFMA floor is 24us (MfmaUtil 5.8% @413us); staging owns the
// kernel (u16 LDS scatter writes -> 1.08e8 bank-conflict cycles ~= 176us-eq,
// VALUBusy 23% = f32->bf16 convert + scatter). Fix: pre-kernels emit
// pre-swizzled bf16 weight tiles + bf16 h into ws; edge kernel stages A (h)
// and all B tiles via global_load_lds width=16 (linear LDS dest, swizzle
// implemented by permuting the per-lane SOURCE address - m173 pattern).
// ea-phase (1 of 9) keeps reg staging. Atomics unchanged: if dur stalls
// >=330us with low VALU, the 51.2M-atomic floor is confirmed -> CSR next.

#define H    128
#define ED   48
#define KIN  305   // 2H + ED + 1
#define NTILE 9    // Wm1 x5, Wm2 x2, Wc1 x2

typedef __attribute__((ext_vector_type(8))) short bf16x8;
typedef __attribute__((ext_vector_type(4))) float f32x4;

__device__ __forceinline__ float silu_f(float v) {
  return v / (1.0f + __expf(-v));
}

__device__ __forceinline__ unsigned short f2bf(float f) {
  unsigned u = __float_as_uint(f);
  return (unsigned short)((u + 0x7FFFu + ((u >> 16) & 1u)) >> 16);
}

__device__ __forceinline__ void gload16(const unsigned short* g, unsigned short* l) {
  __builtin_amdgcn_global_load_lds((const __attribute__((address_space(1))) void*)g,
                                   (__attribute__((address_space(3))) void*)l, 16, 0, 0);
}

// ---- pre-kernel: weights -> pre-swizzled bf16 tiles ----
// Tile t (16KB = 1024 chunks of 16B): LDS-linear chunk o: col = o>>3, ck' = o&7.
// Content = W[k0 + (ck'^(col&7))*8 + j][col], j=0..7 (zero past rows).
__global__ void egnn_wconv(const float* __restrict__ Wm1, const float* __restrict__ Wm2,
                           const float* __restrict__ Wc1, unsigned short* __restrict__ wpre) {
  int c = blockIdx.x * 256 + threadIdx.x;      // global chunk id
  if (c >= NTILE * 1024) return;
  int tile = c >> 10;
  int o    = c & 1023;
  int col  = o >> 3;
  int ck   = (o & 7) ^ (col & 7);
  const float* W; int k0, rows;
  if (tile < 5)      { W = Wm1; k0 = tile * 64;       rows = KIN; }
  else if (tile < 7) { W = Wm2; k0 = (tile - 5) * 64; rows = H; }
  else               { W = Wc1; k0 = (tile - 7) * 64; rows = H; }
  unsigned short v[8];
  #pragma unroll
  for (int j = 0; j < 8; ++j) {
    int k = k0 + ck * 8 + j;
    v[j] = (k < rows) ? f2bf(W[(size_t)k * H + col]) : (unsigned short)0;
  }
  *(uint4*)&wpre[(size_t)c * 8] = *(const uint4*)v;
}

// ---- pre-kernel: h (f32) -> hbf (bf16) ----
__global__ void egnn_hconv(const float* __restrict__ h, unsigned short* __restrict__ hbf,
                           int total) {
  int i = blockIdx.x * 256 + threadIdx.x;      // one 8-elem chunk each
  if (i >= total) return;
  const float* s = h + (size_t)i * 8;
  float4 f0 = *(const float4*)s;
  float4 f1 = *(const float4*)(s + 4);
  unsigned short v[8] = {f2bf(f0.x), f2bf(f0.y), f2bf(f0.z), f2bf(f0.w),
                         f2bf(f1.x), f2bf(f1.y), f2bf(f1.z), f2bf(f1.w)};
  *(uint4*)&hbf[(size_t)i * 8] = *(const uint4*)v;
}

// Build one 16B chunk (8 bf16) from two float4s and store swizzled (ea phase).
__device__ __forceinline__ void store_chunk(unsigned short* sA, int e, int ck,
                                            float4 f0, float4 f1) {
  unsigned short v[8] = {f2bf(f0.x), f2bf(f0.y), f2bf(f0.z), f2bf(f0.w),
                         f2bf(f1.x), f2bf(f1.y), f2bf(f1.z), f2bf(f1.w)};
  *(uint4*)&sA[e * 64 + ((ck ^ (e & 7)) << 3)] = *(const uint4*)v;
}

__device__ __forceinline__ void mfma_tile(const unsigned short* sA, const unsigned short* sB,
                                          int wv, int lr, int lg, f32x4 (&acc)[8][2]) {
  #pragma unroll
  for (int s = 0; s < 2; ++s) {
    int ck = s * 4 + lg;
    int e0 = wv * 32 + lr, e1 = e0 + 16;
    bf16x8 a0 = *(const bf16x8*)&sA[e0 * 64 + ((ck ^ (e0 & 7)) << 3)];
    bf16x8 a1 = *(const bf16x8*)&sA[e1 * 64 + ((ck ^ (e1 & 7)) << 3)];
    #pragma unroll
    for (int ct = 0; ct < 8; ++ct) {
      int col = ct * 16 + lr;
      bf16x8 b = *(const bf16x8*)&sB[col * 64 + ((ck ^ (col & 7)) << 3)];
      acc[ct][0] = __builtin_amdgcn_mfma_f32_16x16x32_bf16(a0, b, acc[ct][0], 0, 0, 0);
      acc[ct][1] = __builtin_amdgcn_mfma_f32_16x16x32_bf16(a1, b, acc[ct][1], 0, 0, 0);
    }
  }
}

__global__ __launch_bounds__(256, 3)
void egnn_edge_mfma(const float* __restrict__ x,
                    const int* __restrict__ ei, const float* __restrict__ ea,
                    const unsigned short* __restrict__ hbf,
                    const unsigned short* __restrict__ wpre,
                    const float* __restrict__ bm1, const float* __restrict__ bm2,
                    const float* __restrict__ bc1,
                    const float* __restrict__ Wc2, const float* __restrict__ bc2,
                    float* __restrict__ agg, float* __restrict__ cdelta, int E)
{
  __shared__ unsigned short sA[128 * 64];  // A tile [e][k] swizzled, 16KB
  __shared__ unsigned short sB[128 * 64];  // B tile W^T [col][k] swizzled, 16KB
  __shared__ int   sSrc[128], sDst[128];
  __shared__ float sR[3][128];

  const int t    = threadIdx.x;
  const int lane = t & 63;
  const int wv   = t >> 6;
  const int lr   = lane & 15;
  const int lg   = lane >> 4;
  const int eb   = blockIdx.x * 128;

  if (t < 128) {
    int e  = eb + t;
    int ec = (e < E) ? e : (E - 1);
    int s  = ei[ec];
    int d  = ei[E + ec];
    sSrc[t] = s; sDst[t] = d;
    float rx = x[s * 3 + 0] - x[d * 3 + 0];
    float ry = x[s * 3 + 1] - x[d * 3 + 1];
    float rz = x[s * 3 + 2] - x[d * 3 + 2];
    sR[0][t] = rx; sR[1][t] = ry; sR[2][t] = rz;
  }
  __syncthreads();   // sSrc/sDst/sR visible to staging

  // ---------------- layer 1: z1 = msg_input @ Wm1 + bm1 ----------------
  f32x4 acc1[8][2];
  #pragma unroll
  for (int ct = 0; ct < 8; ++ct) {
    float b = bm1[ct * 16 + lr];
    #pragma unroll
    for (int rt = 0; rt < 2; ++rt) {
      acc1[ct][rt][0] = b; acc1[ct][rt][1] = b;
      acc1[ct][rt][2] = b; acc1[ct][rt][3] = b;
    }
  }

  // h chunks 0..3: full-DMA staging
  for (int ch = 0; ch < 4; ++ch) {
    __syncthreads();   // previous phase's LDS reads done
    // B tile DMA (tile == ch): 4x 1KB per wave, linear (pre-swizzled source)
    {
      const unsigned short* wsrc = wpre + (size_t)ch * 8192 + wv * 2048 + lane * 8;
      unsigned short* bdst = &sB[wv * 2048];
      #pragma unroll
      for (int i = 0; i < 4; ++i)
        gload16(wsrc + i * 512, bdst + i * 512);
    }
    // A tile DMA from hbf: lane covers (e = base+lane>>3, ck' = lane&7);
    // source address carries the XOR swizzle.
    #pragma unroll
    for (int i = 0; i < 4; ++i) {
      int e   = wv * 32 + i * 8 + (lane >> 3);
      int ckp = lane & 7;
      int row = (ch < 2) ? sSrc[e] : sDst[e];
      const unsigned short* asrc =
          hbf + (size_t)row * 128 + (ch & 1) * 64 + ((ckp ^ (e & 7)) << 3);
      gload16(asrc, &sA[(size_t)(wv * 32 + i * 8) * 64]);
    }
    __syncthreads();   // implicit vmcnt(0) drain covers the DMAs
    mfma_tile(sA, sB, wv, lr, lg, acc1);
  }

  // ea + d2 chunk (k 256..319): reg staging (f32 source), B tile 4 via DMA
  {
    __syncthreads();
    const int se = t >> 1;
    const int sh = t & 1;
    int ecl = (eb + se < E) ? (eb + se) : (E - 1);
    if (sh == 0) {
      const float* __restrict__ ep = &ea[(size_t)ecl * ED];
      #pragma unroll
      for (int c = 0; c < 4; ++c) {
        float4 f0 = *(const float4*)&ep[c * 8];
        float4 f1 = *(const float4*)&ep[c * 8 + 4];
        store_chunk(sA, se, c, f0, f1);
      }
    } else {
      const float* __restrict__ ep = &ea[(size_t)ecl * ED + 32];
      float4 f0 = *(const float4*)&ep[0];
      float4 f1 = *(const float4*)&ep[4];
      store_chunk(sA, se, 4, f0, f1);
      f0 = *(const float4*)&ep[8];
      f1 = *(const float4*)&ep[12];
      store_chunk(sA, se, 5, f0, f1);
      float rx = sR[0][se], ry = sR[1][se], rz = sR[2][se];
      float d2 = rx * rx + ry * ry + rz * rz;
      store_chunk(sA, se, 6, make_float4(d2, 0.f, 0.f, 0.f),
                  make_float4(0.f, 0.f, 0.f, 0.f));
      store_chunk(sA, se, 7, make_float4(0.f, 0.f, 0.f, 0.f),
                  make_float4(0.f, 0.f, 0.f, 0.f));
    }
    const unsigned short* wsrc = wpre + (size_t)4 * 8192 + wv * 2048 + lane * 8;
    unsigned short* bdst = &sB[wv * 2048];
    #pragma unroll
    for (int i = 0; i < 4; ++i)
      gload16(wsrc + i * 512, bdst + i * 512);
    __syncthreads();
    mfma_tile(sA, sB, wv, lr, lg, acc1);
  }

  // ---------------- layer 2: msg = silu(z1) @ Wm2 + bm2 ----------------
  f32x4 acc2[8][2];
  #pragma unroll
  for (int ct = 0; ct < 8; ++ct) {
    float b = bm2[ct * 16 + lr];
    #pragma unroll
    for (int rt = 0; rt < 2; ++rt) {
      acc2[ct][rt][0] = b; acc2[ct][rt][1] = b;
      acc2[ct][rt][2] = b; acc2[ct][rt][3] = b;
    }
  }

  for (int p = 0; p < 2; ++p) {
    __syncthreads();
    #pragma unroll
    for (int ci = 0; ci < 4; ++ci) {
      int ct = p * 4 + ci;
      int kl = ci * 16 + lr;
      int ck = kl >> 3;
      #pragma unroll
      for (int rt = 0; rt < 2; ++rt) {
        #pragma unroll
        for (int r = 0; r < 4; ++r) {
          int e = wv * 32 + rt * 16 + lg * 4 + r;
          sA[e * 64 + ((ck ^ (e & 7)) << 3) + (kl & 7)] = f2bf(silu_f(acc1[ct][rt][r]));
        }
      }
    }
    const unsigned short* wsrc = wpre + (size_t)(5 + p) * 8192 + wv * 2048 + lane * 8;
    unsigned short* bdst = &sB[wv * 2048];
    #pragma unroll
    for (int i = 0; i < 4; ++i)
      gload16(wsrc + i * 512, bdst + i * 512);
    __syncthreads();
    mfma_tile(sA, sB, wv, lr, lg, acc2);
  }

  // ---- agg[dst] += msg (fp32 atomics, C-layout regs)
  #pragma unroll
  for (int ct = 0; ct < 8; ++ct) {
    int col = ct * 16 + lr;
    #pragma unroll
    for (int rt = 0; rt < 2; ++rt) {
      #pragma unroll
      for (int r = 0; r < 4; ++r) {
        int el = wv * 32 + rt * 16 + lg * 4 + r;
        if (eb + el < E)
          atomicAdd(&agg[(size_t)sDst[el] * H + col], acc2[ct][rt][r]);
      }
    }
  }

  // ---------------- layer 3 gate: z3 = msg @ Wc1 + bc1 ----------------
  f32x4 acc3[8][2];
  #pragma unroll
  for (int ct = 0; ct < 8; ++ct) {
    float b = bc1[ct * 16 + lr];
    #pragma unroll
    for (int rt = 0; rt < 2; ++rt) {
      acc3[ct][rt][0] = b; acc3[ct][rt][1] = b;
      acc3[ct][rt][2] = b; acc3[ct][rt][3] = b;
    }
  }

  for (int p = 0; p < 2; ++p) {
    __syncthreads();
    #pragma unroll
    for (int ci = 0; ci < 4; ++ci) {
      int ct = p * 4 + ci;
      int kl = ci * 16 + lr;
      int ck = kl >> 3;
      #pragma unroll
      for (int rt = 0; rt < 2; ++rt) {
        #pragma unroll
        for (int r = 0; r < 4; ++r) {
          int e = wv * 32 + rt * 16 + lg * 4 + r;
          sA[e * 64 + ((ck ^ (e & 7)) << 3) + (kl & 7)] = f2bf(acc2[ct][rt][r]);
        }
      }
    }
    const unsigned short* wsrc = wpre + (size_t)(7 + p) * 8192 + wv * 2048 + lane * 8;
    unsigned short* bdst = &sB[wv * 2048];
    #pragma unroll
    for (int i = 0; i < 4; ++i)
      gload16(wsrc + i * 512, bdst + i * 512);
    __syncthreads();
    mfma_tile(sA, sB, wv, lr, lg, acc3);
  }

  // w = clip(silu(z3) . Wc2 + bc2, -1, 1); coord_delta[dst] += w * r_ij
  float wsum[2][4];
  #pragma unroll
  for (int rt = 0; rt < 2; ++rt)
    #pragma unroll
    for (int r = 0; r < 4; ++r) wsum[rt][r] = 0.f;

  #pragma unroll
  for (int ct = 0; ct < 8; ++ct) {
    float wc = Wc2[ct * 16 + lr];
    #pragma unroll
    for (int rt = 0; rt < 2; ++rt)
      #pragma unroll
      for (int r = 0; r < 4; ++r)
        wsum[rt][r] = fmaf(silu_f(acc3[ct][rt][r]), wc, wsum[rt][r]);
  }
  const float bc2v = bc2[0];
  #pragma unroll
  for (int rt = 0; rt < 2; ++rt) {
    #pragma unroll
    for (int r = 0; r < 4; ++r) {
      float s = wsum[rt][r];
      s += __shfl_xor(s, 1); s += __shfl_xor(s, 2);
      s += __shfl_xor(s, 4); s += __shfl_xor(s, 8);
      int el = wv * 32 + rt * 16 + lg * 4 + r;
      if (lr == 0 && eb + el < E) {
        float wval = fminf(fmaxf(s + bc2v, -1.0f), 1.0f);
        int d = sDst[el];
        atomicAdd(&cdelta[(size_t)d * 3 + 0], wval * sR[0][el]);
        atomicAdd(&cdelta[(size_t)d * 3 + 1], wval * sR[1][el]);
        atomicAdd(&cdelta[(size_t)d * 3 + 2], wval * sR[2][el]);
      }
    }
  }
}

// ---------------- node kernel: unchanged fp32 VALU ----------------
__device__ __forceinline__ void stage_w128(float (*sW)[128], const float* __restrict__ W,
                                           int k0, int rows, int t) {
  #pragma unroll
  for (int i = 0; i < 8; ++i) {
    int f4  = i * 256 + t;
    int row = f4 >> 5;
    int col = (f4 & 31) << 2;
    int gk  = k0 + row;
    float4 v = make_float4(0.f, 0.f, 0.f, 0.f);
    if (gk < rows) v = *(const float4*)&W[(size_t)gk * H + col];
    *(float4*)&sW[row][col] = v;
  }
}

__global__ __launch_bounds__(256, 2)
void egnn_node_kernel(const float* __restrict__ x, const float* __restrict__ h,
                      const float* __restrict__ agg,
                      const float* __restrict__ Wn1, const float* __restrict__ bn1,
                      const float* __restrict__ Wn2, const float* __restrict__ bn2,
                      const float* __restrict__ gamma, const float* __restrict__ beta,
                      const float* __restrict__ cdelta,
                      float* __restrict__ out_x, float* __restrict__ out_h, int N)
{
  __shared__ float sIn[64][64];
  __shared__ float sW[64][128];

  const int t  = threadIdx.x;
  const int tx = t & 15;
  const int ty = t >> 4;
  const int nb = blockIdx.x * 64;

  float acc1[4][8];
  #pragma unroll
  for (int i = 0; i < 4; ++i)
    #pragma unroll
    for (int j = 0; j < 8; ++j)
      acc1[i][j] = bn1[tx * 8 + j];

  const int nl = t >> 2;
  const int q  = t & 3;
  const int ng = nb + nl;

  for (int ch = 0; ch < 4; ++ch) {
    const int k0 = ch * 64;
    __syncthreads();
    const float* __restrict__ src = (ch < 2) ? h : agg;
    const int koff = (k0 & 127) + q * 16;
    if (ng < N) {
      const float* __restrict__ row = &src[(size_t)ng * H + koff];
      #pragma unroll
      for (int v = 0; v < 4; ++v) {
        float4 val = *(const float4*)&row[v * 4];
        int kk = q * 16 + v * 4;
        sIn[kk + 0][nl] = val.x; sIn[kk + 1][nl] = val.y;
        sIn[kk + 2][nl] = val.z; sIn[kk + 3][nl] = val.w;
      }
    } else {
      #pragma unroll
      for (int v = 0; v < 16; ++v) sIn[q * 16 + v][nl] = 0.f;
    }
    stage_w128(sW, Wn1, k0, 2 * H, t);
    __syncthreads();
    #pragma unroll 4
    for (int kk = 0; kk < 64; ++kk) {
      float4 a0 = *(const float4*)&sIn[kk][ty * 4];
      float4 w0 = *(const float4*)&sW[kk][tx * 8];
      float4 w1 = *(const float4*)&sW[kk][tx * 8 + 4];
      float a[4] = {a0.x, a0.y, a0.z, a0.w};
      float w[8] = {w0.x, w0.y, w0.z, w0.w, w1.x, w1.y, w1.z, w1.w};
      #pragma unroll
      for (int i = 0; i < 4; ++i)
        #pragma unroll
        for (int j = 0; j < 8; ++j)
          acc1[i][j] = fmaf(a[i], w[j], acc1[i][j]);
    }
  }

  float sz[4][8];
  #pragma unroll
  for (int i = 0; i < 4; ++i)
    #pragma unroll
    for (int j = 0; j < 8; ++j)
      sz[i][j] = silu_f(acc1[i][j]);

  float acc2[4][8];
  #pragma unroll
  for (int i = 0; i < 4; ++i)
    #pragma unroll
    for (int j = 0; j < 8; ++j)
      acc2[i][j] = bn2[tx * 8 + j];

  for (int pass = 0; pass < 2; ++pass) {
    __syncthreads();
    if ((tx >> 3) == pass) {
      #pragma unroll
      for (int j = 0; j < 8; ++j) {
        int row = (tx & 7) * 8 + j;
        *(float4*)&sIn[row][ty * 4] = make_float4(sz[0][j], sz[1][j], sz[2][j], sz[3][j]);
      }
    }
    stage_w128(sW, Wn2, pass * 64, H, t);
    __syncthreads();
    #pragma unroll 4
    for (int kk = 0; kk < 64; ++kk) {
      float4 a0 = *(const float4*)&sIn[kk][ty * 4];
      float4 w0 = *(const float4*)&sW[kk][tx * 8];
      float4 w1 = *(const float4*)&sW[kk][tx * 8 + 4];
      float a[4] = {a0.x, a0.y, a0.z, a0.w};
      float w[8] = {w0.x, w0.y, w0.z, w0.w, w1.x, w1.y, w1.z, w1.w};
      #pragma unroll
      for (int i = 0; i < 4; ++i)
        #pragma unroll
        for (int j = 0; j < 8; ++j)
          acc2[i][j] = fmaf(a[i], w[j], acc2[i][j]);
    }
  }

  #pragma unroll
  for (int i = 0; i < 4; ++i) {
    int n = nb + ty * 4 + i;
    float4 h0, h1;
    float v[8];
    if (n < N) {
      h0 = *(const float4*)&h[(size_t)n * H + tx * 8];
      h1 = *(const float4*)&h[(size_t)n * H + tx * 8 + 4];
    } else {
      h0 = make_float4(0, 0, 0, 0); h1 = h0;
    }
    v[0] = acc2[i][0] + h0.x; v[1] = acc2[i][1] + h0.y;
    v[2] = acc2[i][2] + h0.z; v[3] = acc2[i][3] + h0.w;
    v[4] = acc2[i][4] + h1.x; v[5] = acc2[i][5] + h1.y;
    v[6] = acc2[i][6] + h1.z; v[7] = acc2[i][7] + h1.w;
    float s = 0.f, sq = 0.f;
    #pragma unroll
    for (int j = 0; j < 8; ++j) { s += v[j]; sq += v[j] * v[j]; }
    #pragma unroll
    for (int m = 1; m < 16; m <<= 1) { s += __shfl_xor(s, m); sq += __shfl_xor(sq, m); }
    float mu  = s * (1.0f / 128.0f);
    float var = sq * (1.0f / 128.0f) - mu * mu;
    float rs  = rsqrtf(var + 1e-5f);
    if (n < N) {
      float4 g0 = *(const float4*)&gamma[tx * 8];
      float4 g1 = *(const float4*)&gamma[tx * 8 + 4];
      float4 b0 = *(const float4*)&beta[tx * 8];
      float4 b1 = *(const float4*)&beta[tx * 8 + 4];
      float4 o0, o1;
      o0.x = (v[0] - mu) * rs * g0.x + b0.x;
      o0.y = (v[1] - mu) * rs * g0.y + b0.y;
      o0.z = (v[2] - mu) * rs * g0.z + b0.z;
      o0.w = (v[3] - mu) * rs * g0.w + b0.w;
      o1.x = (v[4] - mu) * rs * g1.x + b1.x;
      o1.y = (v[5] - mu) * rs * g1.y + b1.y;
      o1.z = (v[6] - mu) * rs * g1.z + b1.z;
      o1.w = (v[7] - mu) * rs * g1.w + b1.w;
      *(float4*)&out_h[(size_t)n * H + tx * 8]     = o0;
      *(float4*)&out_h[(size_t)n * H + tx * 8 + 4] = o1;
    }
  }

  if (t < 192) {
    int nl2 = t / 3, c = t - nl2 * 3;
    int n = nb + nl2;
    if (n < N)
      out_x[(size_t)n * 3 + c] = x[(size_t)n * 3 + c] + cdelta[(size_t)n * 3 + c];
  }
}

extern "C" void kernel_launch(void* const* d_in, const int* in_sizes, int n_in,
                              void* d_out, int out_size, void* d_ws, size_t ws_size,
                              hipStream_t stream) {
  const float* x     = (const float*)d_in[0];
  const float* h     = (const float*)d_in[1];
  const int*   ei    = (const int*)d_in[2];
  const float* ea    = (const float*)d_in[3];
  const float* Wm1   = (const float*)d_in[4];
  const float* bm1   = (const float*)d_in[5];
  const float* Wm2   = (const float*)d_in[6];
  const float* bm2   = (const float*)d_in[7];
  const float* Wn1   = (const float*)d_in[8];
  const float* bn1   = (const float*)d_in[9];
  const float* Wn2   = (const float*)d_in[10];
  const float* bn2   = (const float*)d_in[11];
  const float* Wc1   = (const float*)d_in[12];
  const float* bc1   = (const float*)d_in[13];
  const float* Wc2   = (const float*)d_in[14];
  const float* bc2   = (const float*)d_in[15];
  const float* gamma = (const float*)d_in[16];
  const float* beta  = (const float*)d_in[17];

  const int N = in_sizes[0] / 3;
  const int E = in_sizes[2] / 2;

  float* agg    = (float*)d_ws;                              // N*H f32
  float* cdelta = agg + (size_t)N * H;                       // N*3 f32
  unsigned short* hbf  = (unsigned short*)(cdelta + (size_t)N * 3);  // N*128 bf16
  unsigned short* wpre = hbf + (size_t)N * H;                // 9*8192 bf16
  float* out_x  = (float*)d_out;
  float* out_h  = out_x + (size_t)N * 3;

  hipMemsetAsync(d_ws, 0, (size_t)(N * H + N * 3) * sizeof(float), stream);

  egnn_wconv<<<(NTILE * 1024 + 255) / 256, 256, 0, stream>>>(Wm1, Wm2, Wc1, wpre);
  egnn_hconv<<<(N * 16 + 255) / 256, 256, 0, stream>>>(h, hbf, N * 16);

  const int eblocks = (E + 127) / 128;
  egnn_edge_mfma<<<eblocks, 256, 0, stream>>>(
      x, ei, ea, hbf, wpre, bm1, bm2, bc1, Wc2, bc2, agg, cdelta, E);

  const int nblocks = (N + 63) / 64;
  egnn_node_kernel<<<nblocks, 256, 0, stream>>>(
      x, h, agg, Wn1, bn1, Wn2, bn2, gamma, beta, cdelta, out_x, out_h, N);
}